// Round 7
// baseline (1179.651 us; speedup 1.0000x reference)
//
#include <hip/hip_runtime.h>

// SNU with bias-sign collapse:
//   y_t = (relu(xw_t + 0.8*h*(1-y)) + b > 0).  relu >= 0, so b_h > 0  =>  y == 1 for all t.
// Only columns with b_h <= 0 (~81 of 512) need the GEMM + sequential scan.
//
// R7: pipeline collapse. The 6-dispatch chain was ~150us of serialization overhead
// (R6: 364 total vs ~210 of modeled kernel work). Now ONE mega dispatch does
// gemm + cross-block split-K reduce (device-scope acq-rel counter, last arriver
// sums (p0+p1)+(p2+p3) = bit-identical to R6's reduce4) + ones-fill planes.
// K-loop adds register prefetch of next chunk's staging loads.
//
// ws layout (bytes):
//   0       : int hdr[2] = {count, pc}
//   64      : int idx[256]        compacted h-indices (ascending, padded w/ idx[0])
//   2048    : int cnt[512]        split-K arrival counters (zeroed by compact_cols)
//   4096    : float Wc[512][256]  gathered W columns (512 KB)
//   1<<20   : float xwp[4][T=512][B=128][128]  4 x 32 MB split-K partials, (t,b,j);
//                                              xwp[0] becomes the reduced sum
//   129<<20 : float xwc1[T=512][B=128][128]    overflow direct buffer (j in [128,256)),
//                                              touched only if count > 128 (P ~ 6e-9)

#define DECAYF 0.8f
#define PART   ((size_t)512 * 128 * 128)   // floats per split-K partial
#define PARTF4 (PART / 4)                  // float4s per partial

// ---------- 1. compact: ordered list of columns with b <= 0; zero counters ----------
__global__ __launch_bounds__(512) void compact_cols(const float* __restrict__ bias,
                                                    int* __restrict__ hdr,
                                                    int* __restrict__ idx,
                                                    int* __restrict__ cnt) {
    __shared__ unsigned long long wmask[8];
    const int tid = threadIdx.x;           // 512 threads, H=512
    cnt[tid] = 0;                          // re-zero every call (ws is poisoned)
    const bool p = (bias[tid] <= 0.0f);
    unsigned long long m = __ballot(p);
    const int wid = tid >> 6, lane = tid & 63;
    if (lane == 0) wmask[wid] = m;
    __syncthreads();
    int before = 0, total = 0;
    #pragma unroll
    for (int w = 0; w < 8; w++) {
        int c = __popcll(wmask[w]);
        if (w < wid) before += c;
        total += c;
    }
    if (p) idx[before + __popcll(m & ((1ull << lane) - 1ull))] = tid;
    __syncthreads();
    int idx0 = (total > 0) ? idx[0] : 0;
    if (tid >= total && tid < 256) idx[tid] = idx0;     // pad
    if (tid == 0) {
        int pc = (total + 127) & ~127;
        if (pc < 128) pc = 128;
        if (pc > 256) pc = 256;                          // safety clamp (fits ws)
        hdr[0] = total;
        hdr[1] = pc;
    }
}

// ---------- 2. gather Wc[i][j] = W[i][idx[j]] ----------
__global__ __launch_bounds__(256) void gather_W(const float* __restrict__ W,
                                                const int* __restrict__ idx,
                                                float* __restrict__ Wc) {
    const int i = blockIdx.x;            // 512 rows
    const int j = threadIdx.x;           // 256 cols
    Wc[i * 256 + j] = W[i * 512 + idx[j]];
}

// ---------- 3. mega: gemm + fused split-K reduce + ones-fill ----------
// grid (7, 4, 128):
//   kc 0..3 : split-K gemm chunk (K=128) over cols 0..127 -> xwp[kc]; last arriver
//             per (t-tile,b) reduces 4 partials into xwp[0].
//   kc 4    : overflow (full K, cols 128..255) -> xwc1; exits if pc <= 128.
//   kc 5..6 : ones-fill planes for rows with bias > 0.
__global__ __launch_bounds__(256) void mega(const float* __restrict__ x,
                                            const float* __restrict__ Wc,
                                            const int* __restrict__ hdr,
                                            float* __restrict__ xwp,
                                            float* __restrict__ xwc1,
                                            const float* __restrict__ bias,
                                            float4* __restrict__ out4,
                                            int* __restrict__ cnt) {
    const int kc = blockIdx.x;
    const int tid = threadIdx.x;

    if (kc >= 5) {   // ---- fill planes: 1024 blocks x 8192 float4 each ----
        const float4 ones = make_float4(1.f, 1.f, 1.f, 1.f);
        const int fid = (kc - 5) * 512 + blockIdx.y * 128 + blockIdx.z;
        const size_t base = (size_t)fid * 8192 + tid;   // 1024*8192 = 8M float4 = out
        #pragma unroll
        for (int q = 0; q < 32; q++) {
            size_t f4 = base + (size_t)q * 256;
            int h = (int)((f4 >> 7) & 511);             // (B,H,T): 128 float4 per h-row
            if (bias[h] > 0.0f) out4[f4] = ones;
        }
        return;
    }

    int kbeg, kend, coff;
    float* op;
    if (kc < 4) { kbeg = kc * 128; kend = kbeg + 128; coff = 0;   op = xwp + (size_t)kc * PART; }
    else        { if (hdr[1] <= 128) return;
                  kbeg = 0;        kend = 512;        coff = 128; op = xwc1; }
    const int I = 512, T = 512, NC = 256;
    const int b  = blockIdx.z;
    const int t0 = blockIdx.y * 128;

    __shared__ float As[16][132];  // [i][t]
    __shared__ float Bs[16][132];  // [i][j]

    const int wave = tid >> 6;
    const int lane = tid & 63;
    const int lx = lane & 7;
    const int ly = lane >> 3;
    const int m_base = ((wave >> 1) << 6) + ly * 8;  // t within tile (0..127)
    const int n_base = ((wave & 1) << 6) + lx * 8;   // j within 128 cols

    float acc[8][8];
    #pragma unroll
    for (int i = 0; i < 8; i++)
        #pragma unroll
        for (int j = 0; j < 8; j++) acc[i][j] = 0.f;

    const float* xb = x + (size_t)b * I * T;
    const int row0 = tid >> 5,        c40 = (tid & 31) << 2;          // staging slot j=0
    const int row1 = (tid + 256) >> 5, c41 = ((tid + 256) & 31) << 2; // staging slot j=1

    // register prefetch of first chunk
    float4 pa0 = *(const float4*)(xb + (size_t)(kbeg + row0) * T + t0 + c40);
    float4 pb0 = *(const float4*)(Wc + (size_t)(kbeg + row0) * NC + coff + c40);
    float4 pa1 = *(const float4*)(xb + (size_t)(kbeg + row1) * T + t0 + c41);
    float4 pb1 = *(const float4*)(Wc + (size_t)(kbeg + row1) * NC + coff + c41);

    for (int k0 = kbeg; k0 < kend; k0 += 16) {
        *(float4*)&As[row0][c40] = pa0;
        *(float4*)&Bs[row0][c40] = pb0;
        *(float4*)&As[row1][c41] = pa1;
        *(float4*)&Bs[row1][c41] = pb1;
        __syncthreads();
        if (k0 + 16 < kend) {   // issue next chunk's loads under this chunk's compute
            pa0 = *(const float4*)(xb + (size_t)(k0 + 16 + row0) * T + t0 + c40);
            pb0 = *(const float4*)(Wc + (size_t)(k0 + 16 + row0) * NC + coff + c40);
            pa1 = *(const float4*)(xb + (size_t)(k0 + 16 + row1) * T + t0 + c41);
            pb1 = *(const float4*)(Wc + (size_t)(k0 + 16 + row1) * NC + coff + c41);
        }
        #pragma unroll
        for (int kk = 0; kk < 16; kk++) {
            float a[8], bb[8];
            *(float4*)&a[0]  = *(const float4*)&As[kk][m_base];
            *(float4*)&a[4]  = *(const float4*)&As[kk][m_base + 4];
            *(float4*)&bb[0] = *(const float4*)&Bs[kk][n_base];
            *(float4*)&bb[4] = *(const float4*)&Bs[kk][n_base + 4];
            #pragma unroll
            for (int mi = 0; mi < 8; mi++)
                #pragma unroll
                for (int ni = 0; ni < 8; ni++)
                    acc[mi][ni] = fmaf(a[mi], bb[ni], acc[mi][ni]);
        }
        __syncthreads();
    }

    // store partial, (t,b,j) layout
    #pragma unroll
    for (int mi = 0; mi < 8; mi++) {
        int t = t0 + m_base + mi;
        float* o = op + ((size_t)t * 128 + b) * 128 + n_base;
        *(float4*)o       = *(float4*)&acc[mi][0];
        *(float4*)(o + 4) = *(float4*)&acc[mi][4];
    }

    if (kc == 4) return;   // overflow path: direct, no reduce

    // ---- split-K handshake: last arriver reduces (agent-scope acq-rel) ----
    __threadfence();   // release my partial stores device-wide
    __shared__ int s_old;
    if (tid == 0)
        s_old = __hip_atomic_fetch_add(&cnt[blockIdx.y * 128 + blockIdx.z], 1,
                                       __ATOMIC_ACQ_REL, __HIP_MEMORY_SCOPE_AGENT);
    __syncthreads();
    if (s_old != 3) return;
    __threadfence();   // acquire partners' stores

    // reduce this tile: 128t x 128j = 4096 float4; 16 per thread; order (p0+p1)+(p2+p3)
    float4* xwp4 = (float4*)xwp;
    #pragma unroll
    for (int k = 0; k < 16; k++) {
        int f = tid + k * 256;
        int tt = f >> 5, j4 = f & 31;
        size_t off = ((size_t)(t0 + tt) * 128 + b) * 32 + j4;   // float4 units
        float4 q0 = xwp4[off];
        float4 q1 = xwp4[off + PARTF4];
        float4 q2 = xwp4[off + 2 * PARTF4];
        float4 q3 = xwp4[off + 3 * PARTF4];
        float4 r;
        r.x = (q0.x + q1.x) + (q2.x + q3.x);
        r.y = (q0.y + q1.y) + (q2.y + q3.y);
        r.z = (q0.z + q1.z) + (q2.z + q3.z);
        r.w = (q0.w + q1.w) + (q2.w + q3.w);
        xwp4[off] = r;
    }
}

// ---------- 4. scan: single reduced stream, run recurrence, write spikes ----------
// grid (128 b, 2 jt) x 128 threads. jt=0: j<128 from xwp[0]; jt=1: overflow from xwc1.
__global__ __launch_bounds__(128) void snu_scan(const float* __restrict__ xwp,
                                                const float* __restrict__ xwc1,
                                                const float* __restrict__ bias,
                                                const int* __restrict__ hdr,
                                                const int* __restrict__ idx,
                                                float* __restrict__ out) {
    const int T = 512;
    const int b  = blockIdx.x;
    const int jt = blockIdx.y;
    const int j  = jt * 128 + threadIdx.x;
    if (j >= hdr[0]) return;
    const int h = idx[j];
    const float bv = bias[h];
    float* o = out + ((size_t)b * 512 + h) * (size_t)T;
    const size_t STR = (size_t)128 * 128;    // t-stride in (t,b,j) buffers

    const float* p = (jt == 0) ? (xwp + (size_t)b * 128 + j)
                               : (xwc1 + (size_t)b * 128 + (j - 128));

    float hs = 0.f, y = 0.f;
    float nx[8];
    #pragma unroll
    for (int d = 0; d < 8; d++) nx[d] = p[(size_t)d * STR];

    for (int t0 = 0; t0 < T; t0 += 8) {
        float cur[8], yb[8];
        #pragma unroll
        for (int d = 0; d < 8; d++) cur[d] = nx[d];
        const bool more = (t0 + 8) < T;
        #pragma unroll
        for (int d = 0; d < 8; d++)
            nx[d] = more ? p[(size_t)(t0 + 8 + d) * STR] : 0.f;
        #pragma unroll
        for (int d = 0; d < 8; d++) {
            // (1-y) is exactly 0 or 1 -> relu chain matches reference rounding
            hs = fmaf(DECAYF * hs, 1.f - y, cur[d]);
            hs = fmaxf(hs, 0.f);
            y  = (hs + bv > 0.f) ? 1.f : 0.f;
            yb[d] = y;
        }
        *(float4*)(o + t0)     = *(float4*)&yb[0];
        *(float4*)(o + t0 + 4) = *(float4*)&yb[4];
    }
}

extern "C" void kernel_launch(void* const* d_in, const int* in_sizes, int n_in,
                              void* d_out, int out_size, void* d_ws, size_t ws_size,
                              hipStream_t stream) {
    const float* x    = (const float*)d_in[0];  // (128, 512, 512)
    const float* W    = (const float*)d_in[1];  // (512, 512)
    const float* bias = (const float*)d_in[2];  // (1, 512)
    float* out = (float*)d_out;                 // (B,H,T) = (128, 512, 512)

    char* ws = (char*)d_ws;
    int*   hdr  = (int*)(ws + 0);
    int*   idx  = (int*)(ws + 64);
    int*   cnt  = (int*)(ws + 2048);
    float* Wc   = (float*)(ws + 4096);
    float* xwp  = (float*)(ws + ((size_t)1 << 20));
    float* xwc1 = (float*)(ws + ((size_t)129 << 20));

    compact_cols<<<1, 512, 0, stream>>>(bias, hdr, idx, cnt);
    gather_W<<<512, 256, 0, stream>>>(W, idx, Wc);
    dim3 g1(7, 4, 128);   // (4 kc + overflow + 2 fill planes, t-tiles, B)
    mega<<<g1, 256, 0, stream>>>(x, Wc, hdr, xwp, xwc1, bias, (float4*)out, cnt);
    dim3 g2(128, 2);
    snu_scan<<<g2, 128, 0, stream>>>(xwp, xwc1, bias, hdr, idx, out);
}

// Round 8
// 348.303 us; speedup vs baseline: 3.3869x; 3.3869x over previous
//
#include <hip/hip_runtime.h>

// SNU with bias-sign collapse:
//   y_t = (relu(xw_t + 0.8*h*(1-y)) + b > 0).  relu >= 0, so b_h > 0  =>  y == 1 for all t.
// Only columns with b_h <= 0 (~81 of 512) need the GEMM + sequential scan.
//
// R8: 3 dispatches, no cross-block sync (R7 proved device-scope fences flush L2
// and are ruinous). Compaction is recomputed per block (one wave of ballots).
// reduce4 is folded into the scan via LDS-windowed producer-consumer streaming,
// preserving the (p0+p1)+(p2+p3) sum order bit-for-bit. Fill rides in the scan
// dispatch as disjoint blocks.
//
// ws layout (bytes):
//   4096    : float Wc[512][256]  gathered W columns (512 KB)
//   1<<20   : float xwp[4][T=512][B=128][128]  4 x 32 MB split-K partials, (t,b,j)
//   129<<20 : float xwc1[T=512][B=128][128]    overflow direct buffer (j in [128,256)),
//                                              touched only if count > 128 (P ~ 6e-9)

#define DECAYF 0.8f
#define PART   ((size_t)512 * 128 * 128)   // floats per split-K partial
#define PARTF4 (PART / 4)                  // float4s per partial

// ---------- per-block compaction recompute: one wave of ballots ----------
// Fills idx_s[256] (ascending h with bias<=0, padded with idx_s[0]); returns count.
__device__ __forceinline__ int block_compact(const float* __restrict__ bias,
                                             int* idx_s, int* cnt_s) {
    const int tid = threadIdx.x;
    if (tid < 64) {
        int base = 0;
        #pragma unroll
        for (int w = 0; w < 8; w++) {
            bool p = bias[w * 64 + tid] <= 0.0f;
            unsigned long long m = __ballot(p);
            if (p) idx_s[base + __popcll(m & ((1ull << tid) - 1ull))] = w * 64 + tid;
            base += __popcll(m);
        }
        if (tid == 0) cnt_s[0] = base;
    }
    __syncthreads();
    const int total = cnt_s[0];
    const int i0 = (total > 0) ? idx_s[0] : 0;
    for (int j = total + tid; j < 256; j += blockDim.x) idx_s[j] = i0;
    __syncthreads();
    return total;
}

// ---------- 1. gather Wc[i][j] = W[i][idx[j]] (recomputes compaction) ----------
__global__ __launch_bounds__(256) void gather_W(const float* __restrict__ bias,
                                                const float* __restrict__ W,
                                                float* __restrict__ Wc) {
    __shared__ int idx_s[256];
    __shared__ int cnt_s[1];
    block_compact(bias, idx_s, cnt_s);
    const int i = blockIdx.x;            // 512 rows
    const int j = threadIdx.x;           // 256 cols
    Wc[i * 256 + j] = W[i * 512 + idx_s[j]];
}

// ---------- 2. GEMM: x(B,I,T) x Wc(I,:) -> partials (R6 body, verbatim) ----------
// grid (5, 4, 128) = (kc, t-tiles, B).  kc<4: split-K chunk of 128 over cols 0..127
// into xwp[kc]. kc==4: overflow (full K, cols 128..255) -> xwc1; exits if count<=128.
__global__ __launch_bounds__(256) void gemm_split(const float* __restrict__ x,
                                                  const float* __restrict__ Wc,
                                                  const float* __restrict__ bias,
                                                  float* __restrict__ xwp,
                                                  float* __restrict__ xwc1) {
    const int kc = blockIdx.x;
    const int tid = threadIdx.x;
    int kbeg, kend, coff;
    float* op;
    if (kc < 4) { kbeg = kc * 128; kend = kbeg + 128; coff = 0;   op = xwp + (size_t)kc * PART; }
    else {
        __shared__ int cnt_s;
        if (tid < 64) {
            int tot = 0;
            #pragma unroll
            for (int w = 0; w < 8; w++)
                tot += __popcll(__ballot(bias[w * 64 + tid] <= 0.0f));
            if (tid == 0) cnt_s = tot;
        }
        __syncthreads();
        if (cnt_s <= 128) return;
        kbeg = 0; kend = 512; coff = 128; op = xwc1;
    }
    const int I = 512, T = 512, NC = 256;
    const int b  = blockIdx.z;
    const int t0 = blockIdx.y * 128;

    __shared__ float As[16][132];  // [i][t]
    __shared__ float Bs[16][132];  // [i][j]

    const int wave = tid >> 6;
    const int lane = tid & 63;
    const int lx = lane & 7;
    const int ly = lane >> 3;
    const int m_base = ((wave >> 1) << 6) + ly * 8;  // t within tile (0..127)
    const int n_base = ((wave & 1) << 6) + lx * 8;   // j within 128 cols

    float acc[8][8];
    #pragma unroll
    for (int i = 0; i < 8; i++)
        #pragma unroll
        for (int j = 0; j < 8; j++) acc[i][j] = 0.f;

    const float* xb = x + (size_t)b * I * T;

    for (int k0 = kbeg; k0 < kend; k0 += 16) {
        #pragma unroll
        for (int j = 0; j < 2; j++) {   // stage 16x128 of A and B: 2 float4/thread each
            int id2 = tid + j * 256;
            int row = id2 >> 5;
            int c4  = (id2 & 31) << 2;
            *(float4*)&As[row][c4] = *(const float4*)(xb + (size_t)(k0 + row) * T + t0 + c4);
            *(float4*)&Bs[row][c4] = *(const float4*)(Wc + (size_t)(k0 + row) * NC + coff + c4);
        }
        __syncthreads();
        #pragma unroll
        for (int kk = 0; kk < 16; kk++) {
            float a[8], bb[8];
            *(float4*)&a[0]  = *(const float4*)&As[kk][m_base];
            *(float4*)&a[4]  = *(const float4*)&As[kk][m_base + 4];
            *(float4*)&bb[0] = *(const float4*)&Bs[kk][n_base];
            *(float4*)&bb[4] = *(const float4*)&Bs[kk][n_base + 4];
            #pragma unroll
            for (int mi = 0; mi < 8; mi++)
                #pragma unroll
                for (int ni = 0; ni < 8; ni++)
                    acc[mi][ni] = fmaf(a[mi], bb[ni], acc[mi][ni]);
        }
        __syncthreads();
    }

    #pragma unroll
    for (int mi = 0; mi < 8; mi++) {
        int t = t0 + m_base + mi;
        float* o = op + ((size_t)t * 128 + b) * 128 + n_base;
        *(float4*)o       = *(float4*)&acc[mi][0];
        *(float4*)(o + 4) = *(float4*)&acc[mi][4];
    }
}

// ---------- 3. scan + reduce + fill, one dispatch, 512 threads/block ----------
// blocks [0,512)    : scan role, b = id>>2, jq = id&3 (32 columns each). LDS-windowed
//                     producer-consumer: 512 threads stream 16-t windows of the 4
//                     partials (double-buffered); lanes 0..31 run the recurrence,
//                     summing (p0+p1)+(p2+p3) = bit-identical to R6's reduce4.
// blocks [512,1536) : ones-fill for rows with bias > 0.
// blocks [1536,1664): overflow scan (j in [128,count)), only if count > 128.
__global__ __launch_bounds__(512) void scan_fill(const float* __restrict__ xwp,
                                                 const float* __restrict__ xwc1,
                                                 const float* __restrict__ bias,
                                                 float* __restrict__ out) {
    const int T = 512;
    const int id  = blockIdx.x;
    const int tid = threadIdx.x;

    if (id >= 512 && id < 1536) {   // ---- fill ----
        const float4 ones = make_float4(1.f, 1.f, 1.f, 1.f);
        float4* out4 = (float4*)out;
        const size_t base = (size_t)(id - 512) * 8192 + tid;
        #pragma unroll
        for (int q = 0; q < 16; q++) {
            size_t f4 = base + (size_t)q * 512;      // 1024*8192 = 8M float4 = out
            int h = (int)((f4 >> 7) & 511);          // (B,H,T): 128 float4 per h-row
            if (bias[h] > 0.0f) out4[f4] = ones;
        }
        return;
    }

    __shared__ int idx_s[256];
    __shared__ int cnt_s[1];
    __shared__ float4 win[2][16][4][8];   // [buf][t_off][partial][j4]  16 KB
    const int count = block_compact(bias, idx_s, cnt_s);

    if (id >= 1536) {   // ---- overflow scan: j in [128, count), single stream ----
        if (count <= 128) return;
        if (tid >= count - 128) return;
        const int b = id - 1536;
        const int j = 128 + tid;
        const int h = idx_s[j];
        const float bv = bias[h];
        const float* p = xwc1 + (size_t)b * 128 + tid;
        float* o = out + ((size_t)b * 512 + h) * (size_t)T;
        const size_t STR = (size_t)128 * 128;
        float hs = 0.f, y = 0.f;
        float nx[8];
        #pragma unroll
        for (int d = 0; d < 8; d++) nx[d] = p[(size_t)d * STR];
        for (int t0 = 0; t0 < T; t0 += 8) {
            float cur[8], yb[8];
            #pragma unroll
            for (int d = 0; d < 8; d++) cur[d] = nx[d];
            const bool more = (t0 + 8) < T;
            #pragma unroll
            for (int d = 0; d < 8; d++)
                nx[d] = more ? p[(size_t)(t0 + 8 + d) * STR] : 0.f;
            #pragma unroll
            for (int d = 0; d < 8; d++) {
                hs = fmaf(DECAYF * hs, 1.f - y, cur[d]);
                hs = fmaxf(hs, 0.f);
                y  = (hs + bv > 0.f) ? 1.f : 0.f;
                yb[d] = y;
            }
            *(float4*)(o + t0)     = *(float4*)&yb[0];
            *(float4*)(o + t0 + 4) = *(float4*)&yb[4];
        }
        return;
    }

    // ---- main scan: b = id>>2, columns jq*32 .. jq*32+31 ----
    const int b  = id >> 2;
    const int jq = id & 3;
    if (jq * 32 >= count) return;        // uniform per block

    const float4* xwp4 = (const float4*)xwp;
    // load map: f = tid: j4 = f&7, p = (f>>3)&3, t_off = f>>5  (512 float4/window)
    const int j4l  = tid & 7;
    const int pp   = (tid >> 3) & 3;
    const int toff = tid >> 5;
    const size_t src_base = (size_t)pp * PARTF4 + (size_t)b * 32 + jq * 8 + j4l;

    // compute-lane state (lanes 0..31)
    const int jl = tid;                   // column within quarter
    const int j  = jq * 32 + jl;
    const bool active = (tid < 32) && (j < count);
    const int h = active ? idx_s[j] : 0;
    const float bv = active ? bias[h] : 0.f;
    float* o = out + ((size_t)b * 512 + h) * (size_t)T;
    float hs = 0.f, y = 0.f;

    const float* winf = (const float*)win;

    // prologue: window 0 into buf 0
    {
        float4 v = xwp4[src_base + (size_t)toff * 128 * 32];
        win[0][toff][pp][j4l] = v;
    }
    __syncthreads();

    for (int w = 0; w < 32; w++) {
        const int buf = w & 1;
        float4 v;
        const bool more = (w + 1) < 32;
        if (more)   // issue next window's load now; vmcnt-wait lands at the ds_write below
            v = xwp4[src_base + (size_t)((w + 1) * 16 + toff) * 128 * 32];

        if (active) {
            float yb[16];
            #pragma unroll
            for (int d = 0; d < 16; d++) {
                const int rb = ((buf * 16 + d) * 4) * 32 + jl;
                float s = (winf[rb] + winf[rb + 32]) + (winf[rb + 64] + winf[rb + 96]);
                // (1-y) is exactly 0 or 1 -> relu chain matches reference rounding
                hs = fmaf(DECAYF * hs, 1.f - y, s);
                hs = fmaxf(hs, 0.f);
                y  = (hs + bv > 0.f) ? 1.f : 0.f;
                yb[d] = y;
            }
            const int t0 = w * 16;
            *(float4*)(o + t0)      = *(float4*)&yb[0];
            *(float4*)(o + t0 + 4)  = *(float4*)&yb[4];
            *(float4*)(o + t0 + 8)  = *(float4*)&yb[8];
            *(float4*)(o + t0 + 12) = *(float4*)&yb[12];
        }
        if (more)
            win[buf ^ 1][toff][pp][j4l] = v;
        __syncthreads();
    }
}

extern "C" void kernel_launch(void* const* d_in, const int* in_sizes, int n_in,
                              void* d_out, int out_size, void* d_ws, size_t ws_size,
                              hipStream_t stream) {
    const float* x    = (const float*)d_in[0];  // (128, 512, 512)
    const float* W    = (const float*)d_in[1];  // (512, 512)
    const float* bias = (const float*)d_in[2];  // (1, 512)
    float* out = (float*)d_out;                 // (B,H,T) = (128, 512, 512)

    char* ws = (char*)d_ws;
    float* Wc   = (float*)(ws + 4096);
    float* xwp  = (float*)(ws + ((size_t)1 << 20));
    float* xwc1 = (float*)(ws + ((size_t)129 << 20));

    gather_W<<<512, 256, 0, stream>>>(bias, W, Wc);
    dim3 g1(5, 4, 128);   // (4 kc + overflow, t-tiles, B)
    gemm_split<<<g1, 256, 0, stream>>>(x, Wc, bias, xwp, xwc1);
    scan_fill<<<1664, 512, 0, stream>>>(xwp, xwc1, bias, out);
}